// Round 9
// baseline (65.551 us; speedup 1.0000x reference)
//
#include <hip/hip_runtime.h>
#include <hip/hip_bf16.h>
#include <math.h>

#define B_N 2
#define S_N 8
#define H_N 32
#define W_N 32
#define DIM_N 256
#define NPOS (B_N * S_N * H_N * W_N)       // 16384
#define NP (NPOS * DIM_N)                  // 4194304
#define SCALE_F 0.1767766952966369f        // 32^-0.5

typedef __attribute__((ext_vector_type(8))) short bf16x8;
typedef __attribute__((ext_vector_type(4))) float f32x4;

__device__ __forceinline__ unsigned short f2b(float f) {
    __hip_bfloat16 h = __float2bfloat16(f);
    return __builtin_bit_cast(unsigned short, h);
}
__device__ __forceinline__ unsigned pk2(float a, float b) {
    return (unsigned)f2b(a) | ((unsigned)f2b(b) << 16);
}
__device__ __forceinline__ float bl(unsigned u) { return __uint_as_float(u << 16); }
__device__ __forceinline__ float bh(unsigned u) { return __uint_as_float(u & 0xffff0000u); }

// ---------------- weight transpose + convert: Wt[n][k] = bf16(W[k][n]) ----------------
__global__ __launch_bounds__(256)
void wtrans_kernel(const float* __restrict__ Wq, const float* __restrict__ Wk,
                   const float* __restrict__ Wv, const float* __restrict__ Wo,
                   unsigned short* __restrict__ wt)
{
    int mat = blockIdx.y;
    const float* W = (mat == 0) ? Wq : (mat == 1) ? Wk : (mat == 2) ? Wv : Wo;
    unsigned short* Wt = wt + (size_t)mat * 65536;
    int tile = blockIdx.x;                 // 64 tiles of 32x32
    int tk = tile >> 3, tn = tile & 7;
    __shared__ float t[32][33];
    int c = threadIdx.x & 31;
    int r0 = (threadIdx.x >> 5) * 4;
#pragma unroll
    for (int i = 0; i < 4; ++i)
        t[r0 + i][c] = W[(size_t)(tk * 32 + r0 + i) * 256 + tn * 32 + c];
    __syncthreads();
#pragma unroll
    for (int i = 0; i < 4; ++i)
        Wt[(size_t)(tn * 32 + r0 + i) * 256 + tk * 32 + c] = f2b(t[c][r0 + i]);
}

// ---------------- proj GEMM: 128x128 tile, 4 waves (2x2), BK=64 ----------------
// B staged via global_load_lds (linear LDS, inverse-swizzled global source,
// XOR-swizzled ds_read). A fp32, converted inline through registers.
// out head-major bf16 [head][pos][32].   (R7 structure — best measured)
__global__ __launch_bounds__(256, 3)
void proj_mfma(const float* __restrict__ x, const float* __restrict__ q,
               const unsigned short* __restrict__ wt, const float* __restrict__ bv,
               unsigned short* __restrict__ qh, unsigned short* __restrict__ kh,
               unsigned short* __restrict__ vh)
{
    __shared__ unsigned short Al[128][72];   // padded: 2-way max on frag reads
    __shared__ unsigned short Bl[128][64];   // linear: global_load_lds dest

    const int bx = blockIdx.x;               // 128 rowtiles x 2 coltiles x 3 mats
    const int z = bx >> 8;                   // 0:q 1:k 2:v
    const int rem = bx & 255;
    const int row0 = (rem >> 1) * 128;
    const int col0 = (rem & 1) * 128;
    const float* A = (z == 0) ? q : x;
    const unsigned short* Wtm = wt + (size_t)z * 65536;
    unsigned short* outp = (z == 0) ? qh : (z == 1) ? kh : vh;
    const float* bias = (z == 2) ? bv : nullptr;

    const int tid = threadIdx.x;
    const int lane = tid & 63;
    const int wid = tid >> 6;
    const int wr = wid >> 1, wc = wid & 1;   // wave tile: 64x64
    const int l15 = lane & 15, l4 = lane >> 4;

    f32x4 acc[4][4];
#pragma unroll
    for (int m = 0; m < 4; ++m)
#pragma unroll
        for (int n = 0; n < 4; ++n) acc[m][n] = (f32x4){0.f, 0.f, 0.f, 0.f};

    for (int kt = 0; kt < DIM_N; kt += 64) {
        // B: 128 rows x 64 k via global_load_lds; content at physical unit u of
        // row r is logical unit u^(r&7)  (read side applies the same XOR)
#pragma unroll
        for (int i = 0; i < 4; ++i) {
            int c = wid * 4 + i;             // 1KB chunk, wave-uniform
            int o = c * 64 + lane;           // 16B-unit index 0..1023
            int row = o >> 3, u = o & 7;
            int lu = u ^ (row & 7);
            const unsigned short* g =
                &Wtm[(size_t)(col0 + row) * DIM_N + kt + lu * 8];
            __builtin_amdgcn_global_load_lds(
                (const __attribute__((address_space(1))) unsigned int*)g,
                (__attribute__((address_space(3))) unsigned int*)&Bl[c * 8][0],
                16, 0, 0);
        }
        // A: 128 rows x 64 k fp32 -> bf16, fully-coalesced float4 loads
#pragma unroll
        for (int i = 0; i < 8; ++i) {
            int o = i * 256 + tid;           // float4-unit index 0..2047
            int row = o >> 4, qq = o & 15;
            float4 f = *(const float4*)&A[(size_t)(row0 + row) * DIM_N + kt + qq * 4];
            uint2 v;
            v.x = pk2(f.x, f.y);
            v.y = pk2(f.z, f.w);
            *(uint2*)&Al[row][qq * 4] = v;
        }
        __syncthreads();
#pragma unroll
        for (int ks = 0; ks < 2; ++ks) {
            bf16x8 af[4], bfr[4];
#pragma unroll
            for (int m = 0; m < 4; ++m)
                af[m] = *(const bf16x8*)&Al[wr * 64 + m * 16 + l15][ks * 32 + l4 * 8];
#pragma unroll
            for (int n = 0; n < 4; ++n) {
                int row = wc * 64 + n * 16 + l15;
                int su = (ks * 4 + l4) ^ (row & 7);
                bfr[n] = *(const bf16x8*)&Bl[row][su * 8];
            }
#pragma unroll
            for (int m = 0; m < 4; ++m)
#pragma unroll
                for (int n = 0; n < 4; ++n)
                    acc[m][n] = __builtin_amdgcn_mfma_f32_16x16x32_bf16(
                        af[m], bfr[n], acc[m][n], 0, 0, 0);
        }
        __syncthreads();
    }

    // D layout: col = lane&15, row = (lane>>4)*4 + reg  [m89]
#pragma unroll
    for (int n = 0; n < 4; ++n) {
        int col = col0 + wc * 64 + n * 16 + l15;
        float bb = bias ? bias[col] : 0.f;
        int head = col >> 5, dh = col & 31;
#pragma unroll
        for (int m = 0; m < 4; ++m) {
#pragma unroll
            for (int rg = 0; rg < 4; ++rg) {
                int row = row0 + wr * 64 + m * 16 + l4 * 4 + rg;
                outp[((size_t)head * NPOS + row) * 32 + dh] =
                    f2b(acc[m][n][rg] + bb);
            }
        }
    }
}

// ---------------- fused local 3D attention + output projection ----------------
// Block = (b,s,h) row, 256 threads / 4 waves. XCD-chunked swizzle for L2
// locality. Phase-1 branchless. Phase-2: Wo fragments read DIRECTLY from
// global (128 KB, L2-resident) — no LDS staging, no per-kt barriers, so the
// compiler can pipeline B-loads of kt+1 under MFMA of kt.
__global__ __launch_bounds__(256, 2)
void attn_fused(const unsigned short* __restrict__ qh, const unsigned short* __restrict__ kh,
                const unsigned short* __restrict__ vh, const unsigned short* __restrict__ wt3,
                const float* __restrict__ bo, float* __restrict__ out)
{
    __shared__ unsigned short aol[32 * 256];    // 16 KB attention-output tile

    int p = blockIdx.x;
    int bix = (p & 7) * 64 + (p >> 3);          // bijective: 512 = 8 * 64
    int h = bix & 31, s = (bix >> 5) & 7, b = bix >> 8;
    int n = threadIdx.x >> 5;       // head
    int w = threadIdx.x & 31;

    size_t rowbase = (((size_t)b * S_N + s) * H_N + h) * W_N;
    size_t pos = rowbase + w;
    const unsigned short* qrow = qh + ((size_t)n * NPOS + pos) * 32;
    float qv[32];
#pragma unroll
    for (int j = 0; j < 4; ++j) {
        uint4 u = ((const uint4*)qrow)[j];
        qv[j * 8 + 0] = bl(u.x); qv[j * 8 + 1] = bh(u.x);
        qv[j * 8 + 2] = bl(u.y); qv[j * 8 + 3] = bh(u.y);
        qv[j * 8 + 4] = bl(u.z); qv[j * 8 + 5] = bh(u.z);
        qv[j * 8 + 6] = bl(u.w); qv[j * 8 + 7] = bh(u.w);
    }

    float dots[27];
#pragma unroll
    for (int dz = 0; dz < 3; ++dz)
#pragma unroll
        for (int dy = 0; dy < 3; ++dy) {
            int ns = s + dz - 1, nh = h + dy - 1;
            bool rowok = (unsigned)ns < S_N && (unsigned)nh < H_N;
            size_t rb = rowok ? ((((size_t)b * S_N + ns) * H_N + nh) * W_N)
                              : rowbase;
            const unsigned short* base = kh + ((size_t)n * NPOS + rb + w) * 32;
            uint4 kr[3][4];
#pragma unroll
            for (int dx = 0; dx < 3; ++dx) {
                const uint4* kp = (const uint4*)(base + (dx - 1) * 32);
#pragma unroll
                for (int j = 0; j < 4; ++j) kr[dx][j] = kp[j];
            }
#pragma unroll
            for (int dx = 0; dx < 3; ++dx) {
                float acc = 0.f;
#pragma unroll
                for (int j = 0; j < 4; ++j) {
                    uint4 u = kr[dx][j];
                    acc = fmaf(qv[j * 8 + 0], bl(u.x), acc);
                    acc = fmaf(qv[j * 8 + 1], bh(u.x), acc);
                    acc = fmaf(qv[j * 8 + 2], bl(u.y), acc);
                    acc = fmaf(qv[j * 8 + 3], bh(u.y), acc);
                    acc = fmaf(qv[j * 8 + 4], bl(u.z), acc);
                    acc = fmaf(qv[j * 8 + 5], bh(u.z), acc);
                    acc = fmaf(qv[j * 8 + 6], bl(u.w), acc);
                    acc = fmaf(qv[j * 8 + 7], bh(u.w), acc);
                }
                int nw = w + dx - 1;
                bool ok = rowok && (unsigned)nw < W_N;
                dots[(dz * 3 + dy) * 3 + dx] = ok ? acc * SCALE_F : -1e30f;
            }
        }

    float m = dots[0];
#pragma unroll
    for (int i = 1; i < 27; ++i) m = fmaxf(m, dots[i]);
    float den = 0.f;
#pragma unroll
    for (int i = 0; i < 27; ++i) {
        float p2 = __expf(dots[i] - m);     // masked: exp(-1e30) == 0 exactly
        dots[i] = p2;
        den += p2;
    }
    float inv = 1.f / den;

    float ov[32];
#pragma unroll
    for (int i = 0; i < 32; ++i) ov[i] = 0.f;
#pragma unroll
    for (int dz = 0; dz < 3; ++dz)
#pragma unroll
        for (int dy = 0; dy < 3; ++dy) {
            int ns = s + dz - 1, nh = h + dy - 1;
            bool rowok = (unsigned)ns < S_N && (unsigned)nh < H_N;
            size_t rb = rowok ? ((((size_t)b * S_N + ns) * H_N + nh) * W_N)
                              : rowbase;
            const unsigned short* base = vh + ((size_t)n * NPOS + rb + w) * 32;
            uint4 vr[3][4];
#pragma unroll
            for (int dx = 0; dx < 3; ++dx) {
                const uint4* vp = (const uint4*)(base + (dx - 1) * 32);
#pragma unroll
                for (int j = 0; j < 4; ++j) vr[dx][j] = vp[j];
            }
#pragma unroll
            for (int dx = 0; dx < 3; ++dx) {
                float pw = dots[(dz * 3 + dy) * 3 + dx];   // 0 for masked
#pragma unroll
                for (int j = 0; j < 4; ++j) {
                    uint4 u = vr[dx][j];
                    ov[j * 8 + 0] = fmaf(pw, bl(u.x), ov[j * 8 + 0]);
                    ov[j * 8 + 1] = fmaf(pw, bh(u.x), ov[j * 8 + 1]);
                    ov[j * 8 + 2] = fmaf(pw, bl(u.y), ov[j * 8 + 2]);
                    ov[j * 8 + 3] = fmaf(pw, bh(u.y), ov[j * 8 + 3]);
                    ov[j * 8 + 4] = fmaf(pw, bl(u.z), ov[j * 8 + 4]);
                    ov[j * 8 + 5] = fmaf(pw, bh(u.z), ov[j * 8 + 5]);
                    ov[j * 8 + 6] = fmaf(pw, bl(u.w), ov[j * 8 + 6]);
                    ov[j * 8 + 7] = fmaf(pw, bh(u.w), ov[j * 8 + 7]);
                }
            }
        }

    // attention tile -> LDS, pos-major rows, 16B units XOR-swizzled by row
#pragma unroll
    for (int j = 0; j < 4; ++j) {
        uint4 o;
        o.x = pk2(ov[j * 8 + 0] * inv, ov[j * 8 + 1] * inv);
        o.y = pk2(ov[j * 8 + 2] * inv, ov[j * 8 + 3] * inv);
        o.z = pk2(ov[j * 8 + 4] * inv, ov[j * 8 + 5] * inv);
        o.w = pk2(ov[j * 8 + 6] * inv, ov[j * 8 + 7] * inv);
        int unit = n * 4 + j;                   // 16B unit within the 512B row
        int su = unit ^ (w & 7);
        *(uint4*)&aol[w * 256 + su * 8] = o;
    }
    __syncthreads();                            // aol complete (only barrier)

    // ---- phase 2: out[32,256] = aol @ Wo + bo, Wo direct from L2 ----
    const int lane = threadIdx.x & 63;
    const int wv = threadIdx.x >> 6;            // wave -> col block of 64
    const int l15 = lane & 15, l4 = lane >> 4;

    f32x4 acc[2][4];
#pragma unroll
    for (int m2 = 0; m2 < 2; ++m2)
#pragma unroll
        for (int n2 = 0; n2 < 4; ++n2) acc[m2][n2] = (f32x4){0.f, 0.f, 0.f, 0.f};

    const unsigned short* wbase = wt3 + (size_t)(wv * 64 + l15) * DIM_N + l4 * 8;

#pragma unroll
    for (int kt = 0; kt < 4; ++kt) {
#pragma unroll
        for (int ks = 0; ks < 2; ++ks) {
            int k0 = kt * 64 + ks * 32;
            bf16x8 af[2], bfr[4];
#pragma unroll
            for (int n2 = 0; n2 < 4; ++n2)
                bfr[n2] = *(const bf16x8*)&wbase[(size_t)(n2 * 16) * DIM_N + k0];
#pragma unroll
            for (int m2 = 0; m2 < 2; ++m2) {
                int r = m2 * 16 + l15;
                int unit = kt * 8 + ks * 4 + l4;
                int su = unit ^ (r & 7);
                af[m2] = *(const bf16x8*)&aol[r * 256 + su * 8];
            }
#pragma unroll
            for (int m2 = 0; m2 < 2; ++m2)
#pragma unroll
                for (int n2 = 0; n2 < 4; ++n2)
                    acc[m2][n2] = __builtin_amdgcn_mfma_f32_16x16x32_bf16(
                        af[m2], bfr[n2], acc[m2][n2], 0, 0, 0);
        }
    }

#pragma unroll
    for (int n2 = 0; n2 < 4; ++n2) {
        int col = wv * 64 + n2 * 16 + l15;
        float bb = bo[col];
#pragma unroll
        for (int m2 = 0; m2 < 2; ++m2) {
#pragma unroll
            for (int rg = 0; rg < 4; ++rg) {
                int row = m2 * 16 + l4 * 4 + rg;
                out[(rowbase + row) * DIM_N + col] = acc[m2][n2][rg] + bb;
            }
        }
    }
}

// ---------------- launch ----------------
extern "C" void kernel_launch(void* const* d_in, const int* in_sizes, int n_in,
                              void* d_out, int out_size, void* d_ws, size_t ws_size,
                              hipStream_t stream)
{
    const float* xin = (const float*)d_in[0];
    const float* qin = (const float*)d_in[1];
    const float* Wq  = (const float*)d_in[2];
    const float* Wk  = (const float*)d_in[3];
    const float* Wv  = (const float*)d_in[4];
    const float* bv  = (const float*)d_in[5];
    const float* Wo  = (const float*)d_in[6];
    const float* bo  = (const float*)d_in[7];
    float* out = (float*)d_out;

    unsigned short* ws = (unsigned short*)d_ws;
    unsigned short* wt = ws;                        // 4 * 65536
    unsigned short* qh = wt + (size_t)4 * 65536;    // head-major [8][NPOS][32]
    unsigned short* kh = qh + (size_t)NP;
    unsigned short* vh = kh + (size_t)NP;

    dim3 gw(64, 4);
    wtrans_kernel<<<gw, 256, 0, stream>>>(Wq, Wk, Wv, Wo, wt);

    proj_mfma<<<768, 256, 0, stream>>>(xin, qin, wt, bv, qh, kh, vh);

    attn_fused<<<B_N * S_N * H_N, 256, 0, stream>>>(qh, kh, vh, wt + 3 * 65536, bo, out);
}

// Round 10
// 60.198 us; speedup vs baseline: 1.0889x; 1.0889x over previous
//
#include <hip/hip_runtime.h>
#include <hip/hip_bf16.h>
#include <math.h>

#define B_N 2
#define S_N 8
#define H_N 32
#define W_N 32
#define DIM_N 256
#define NPOS (B_N * S_N * H_N * W_N)       // 16384
#define NP (NPOS * DIM_N)                  // 4194304
#define SCALE_F 0.1767766952966369f        // 32^-0.5

typedef __attribute__((ext_vector_type(8))) short bf16x8;
typedef __attribute__((ext_vector_type(4))) float f32x4;

__device__ __forceinline__ unsigned short f2b(float f) {
    __hip_bfloat16 h = __float2bfloat16(f);
    return __builtin_bit_cast(unsigned short, h);
}
__device__ __forceinline__ unsigned pk2(float a, float b) {
    return (unsigned)f2b(a) | ((unsigned)f2b(b) << 16);
}
__device__ __forceinline__ float bl(unsigned u) { return __uint_as_float(u << 16); }
__device__ __forceinline__ float bh(unsigned u) { return __uint_as_float(u & 0xffff0000u); }

// ---------------- weight transpose + convert: Wt[n][k] = bf16(W[k][n]) ----------------
__global__ __launch_bounds__(256)
void wtrans_kernel(const float* __restrict__ Wq, const float* __restrict__ Wk,
                   const float* __restrict__ Wv, const float* __restrict__ Wo,
                   unsigned short* __restrict__ wt)
{
    int mat = blockIdx.y;
    const float* W = (mat == 0) ? Wq : (mat == 1) ? Wk : (mat == 2) ? Wv : Wo;
    unsigned short* Wt = wt + (size_t)mat * 65536;
    int tile = blockIdx.x;                 // 64 tiles of 32x32
    int tk = tile >> 3, tn = tile & 7;
    __shared__ float t[32][33];
    int c = threadIdx.x & 31;
    int r0 = (threadIdx.x >> 5) * 4;
#pragma unroll
    for (int i = 0; i < 4; ++i)
        t[r0 + i][c] = W[(size_t)(tk * 32 + r0 + i) * 256 + tn * 32 + c];
    __syncthreads();
#pragma unroll
    for (int i = 0; i < 4; ++i)
        Wt[(size_t)(tn * 32 + r0 + i) * 256 + tk * 32 + c] = f2b(t[c][r0 + i]);
}

// ---------------- proj GEMM: 64x256 tile, 8 waves (2r x 4n of 32x64), BK=64 --------
// A read exactly once (full-N tile). B staged via global_load_lds (linear LDS
// dest, inverse-swizzled global source, XOR-swizzled ds_read). A fp32 -> bf16
// inline through registers. 42KB LDS + launch_bounds(512,6) -> 3 blocks/CU,
// 24 waves/CU for latency hiding. out head-major bf16 [head][pos][32].
__global__ __launch_bounds__(512, 6)
void proj_mfma(const float* __restrict__ x, const float* __restrict__ q,
               const unsigned short* __restrict__ wt, const float* __restrict__ bv,
               unsigned short* __restrict__ qh, unsigned short* __restrict__ kh,
               unsigned short* __restrict__ vh)
{
    __shared__ unsigned short Al[64][72];       // padded: 2-way max on frag reads
    __shared__ unsigned short Bl[256][64];      // linear: global_load_lds dest

    const int bx = blockIdx.x;                  // 256 rowtiles x 3 mats
    const int z = bx >> 8;                      // 0:q 1:k 2:v
    const int row0 = (bx & 255) * 64;
    const float* A = (z == 0) ? q : x;
    const unsigned short* Wtm = wt + (size_t)z * 65536;
    unsigned short* outp = (z == 0) ? qh : (z == 1) ? kh : vh;
    const float* bias = (z == 2) ? bv : nullptr;

    const int tid = threadIdx.x;
    const int lane = tid & 63;
    const int wid = tid >> 6;
    const int wr = wid >> 2, wn = wid & 3;      // wave tile: 32 rows x 64 cols
    const int l15 = lane & 15, l4 = lane >> 4;

    f32x4 acc[2][4];
#pragma unroll
    for (int m = 0; m < 2; ++m)
#pragma unroll
        for (int n = 0; n < 4; ++n) acc[m][n] = (f32x4){0.f, 0.f, 0.f, 0.f};

    for (int kt = 0; kt < DIM_N; kt += 64) {
        // B: 256 rows x 64 k via global_load_lds; physical unit u of row r
        // holds logical unit u^(r&7); read side applies the same XOR.
#pragma unroll
        for (int i = 0; i < 4; ++i) {
            int c = wid * 4 + i;                // chunk 0..31 (8 rows each)
            int o = c * 64 + lane;              // 16B-unit index 0..2047
            int row = o >> 3, u = o & 7;
            int lu = u ^ (row & 7);
            const unsigned short* g =
                &Wtm[(size_t)row * DIM_N + kt + lu * 8];
            __builtin_amdgcn_global_load_lds(
                (const __attribute__((address_space(1))) unsigned int*)g,
                (__attribute__((address_space(3))) unsigned int*)&Bl[c * 8][0],
                16, 0, 0);
        }
        // A: 64 rows x 64 k fp32 -> bf16; 1024 float4 units, 2 per thread
#pragma unroll
        for (int i = 0; i < 2; ++i) {
            int o = i * 512 + tid;
            int row = o >> 4, qq = o & 15;
            float4 f = *(const float4*)&A[(size_t)(row0 + row) * DIM_N + kt + qq * 4];
            uint2 v;
            v.x = pk2(f.x, f.y);
            v.y = pk2(f.z, f.w);
            *(uint2*)&Al[row][qq * 4] = v;
        }
        __syncthreads();
#pragma unroll
        for (int ks = 0; ks < 2; ++ks) {
            bf16x8 af[2], bfr[4];
#pragma unroll
            for (int m = 0; m < 2; ++m)
                af[m] = *(const bf16x8*)&Al[wr * 32 + m * 16 + l15][ks * 32 + l4 * 8];
#pragma unroll
            for (int n = 0; n < 4; ++n) {
                int row = wn * 64 + n * 16 + l15;
                int su = (ks * 4 + l4) ^ (row & 7);
                bfr[n] = *(const bf16x8*)&Bl[row][su * 8];
            }
#pragma unroll
            for (int m = 0; m < 2; ++m)
#pragma unroll
                for (int n = 0; n < 4; ++n)
                    acc[m][n] = __builtin_amdgcn_mfma_f32_16x16x32_bf16(
                        af[m], bfr[n], acc[m][n], 0, 0, 0);
        }
        __syncthreads();
    }

    // D layout: col = lane&15, row = (lane>>4)*4 + reg  [m89]
#pragma unroll
    for (int n = 0; n < 4; ++n) {
        int col = wn * 64 + n * 16 + l15;
        float bb = bias ? bias[col] : 0.f;
        int head = col >> 5, dh = col & 31;
#pragma unroll
        for (int m = 0; m < 2; ++m) {
#pragma unroll
            for (int rg = 0; rg < 4; ++rg) {
                int row = row0 + wr * 32 + m * 16 + l4 * 4 + rg;
                outp[((size_t)head * NPOS + row) * 32 + dh] =
                    f2b(acc[m][n][rg] + bb);
            }
        }
    }
}

// ---------------- fused local 3D attention + output projection ----------------
// Block = (b,s,h) row, 256 threads / 4 waves. XCD-chunked swizzle for L2
// locality. Phase-1 branchless. Phase-2: Wo K-tiles LDS-staged (R7 form —
// direct-from-L2 Wo regressed at this occupancy, R9).
__global__ __launch_bounds__(256, 2)
void attn_fused(const unsigned short* __restrict__ qh, const unsigned short* __restrict__ kh,
                const unsigned short* __restrict__ vh, const unsigned short* __restrict__ wt3,
                const float* __restrict__ bo, float* __restrict__ out)
{
    __shared__ unsigned short aol[32 * 256];    // 16 KB attention-output tile
    __shared__ unsigned short Bl[256][72];      // 36 KB Wo K-tile

    int p = blockIdx.x;
    int bix = (p & 7) * 64 + (p >> 3);          // bijective: 512 = 8 * 64
    int h = bix & 31, s = (bix >> 5) & 7, b = bix >> 8;
    int n = threadIdx.x >> 5;       // head
    int w = threadIdx.x & 31;

    size_t rowbase = (((size_t)b * S_N + s) * H_N + h) * W_N;
    size_t pos = rowbase + w;
    const unsigned short* qrow = qh + ((size_t)n * NPOS + pos) * 32;
    float qv[32];
#pragma unroll
    for (int j = 0; j < 4; ++j) {
        uint4 u = ((const uint4*)qrow)[j];
        qv[j * 8 + 0] = bl(u.x); qv[j * 8 + 1] = bh(u.x);
        qv[j * 8 + 2] = bl(u.y); qv[j * 8 + 3] = bh(u.y);
        qv[j * 8 + 4] = bl(u.z); qv[j * 8 + 5] = bh(u.z);
        qv[j * 8 + 6] = bl(u.w); qv[j * 8 + 7] = bh(u.w);
    }

    float dots[27];
#pragma unroll
    for (int dz = 0; dz < 3; ++dz)
#pragma unroll
        for (int dy = 0; dy < 3; ++dy) {
            int ns = s + dz - 1, nh = h + dy - 1;
            bool rowok = (unsigned)ns < S_N && (unsigned)nh < H_N;
            size_t rb = rowok ? ((((size_t)b * S_N + ns) * H_N + nh) * W_N)
                              : rowbase;
            const unsigned short* base = kh + ((size_t)n * NPOS + rb + w) * 32;
            uint4 kr[3][4];
#pragma unroll
            for (int dx = 0; dx < 3; ++dx) {
                const uint4* kp = (const uint4*)(base + (dx - 1) * 32);
#pragma unroll
                for (int j = 0; j < 4; ++j) kr[dx][j] = kp[j];
            }
#pragma unroll
            for (int dx = 0; dx < 3; ++dx) {
                float acc = 0.f;
#pragma unroll
                for (int j = 0; j < 4; ++j) {
                    uint4 u = kr[dx][j];
                    acc = fmaf(qv[j * 8 + 0], bl(u.x), acc);
                    acc = fmaf(qv[j * 8 + 1], bh(u.x), acc);
                    acc = fmaf(qv[j * 8 + 2], bl(u.y), acc);
                    acc = fmaf(qv[j * 8 + 3], bh(u.y), acc);
                    acc = fmaf(qv[j * 8 + 4], bl(u.z), acc);
                    acc = fmaf(qv[j * 8 + 5], bh(u.z), acc);
                    acc = fmaf(qv[j * 8 + 6], bl(u.w), acc);
                    acc = fmaf(qv[j * 8 + 7], bh(u.w), acc);
                }
                int nw = w + dx - 1;
                bool ok = rowok && (unsigned)nw < W_N;
                dots[(dz * 3 + dy) * 3 + dx] = ok ? acc * SCALE_F : -1e30f;
            }
        }

    float m = dots[0];
#pragma unroll
    for (int i = 1; i < 27; ++i) m = fmaxf(m, dots[i]);
    float den = 0.f;
#pragma unroll
    for (int i = 0; i < 27; ++i) {
        float p2 = __expf(dots[i] - m);     // masked: exp(-1e30) == 0 exactly
        dots[i] = p2;
        den += p2;
    }
    float inv = 1.f / den;

    float ov[32];
#pragma unroll
    for (int i = 0; i < 32; ++i) ov[i] = 0.f;
#pragma unroll
    for (int dz = 0; dz < 3; ++dz)
#pragma unroll
        for (int dy = 0; dy < 3; ++dy) {
            int ns = s + dz - 1, nh = h + dy - 1;
            bool rowok = (unsigned)ns < S_N && (unsigned)nh < H_N;
            size_t rb = rowok ? ((((size_t)b * S_N + ns) * H_N + nh) * W_N)
                              : rowbase;
            const unsigned short* base = vh + ((size_t)n * NPOS + rb + w) * 32;
            uint4 vr[3][4];
#pragma unroll
            for (int dx = 0; dx < 3; ++dx) {
                const uint4* vp = (const uint4*)(base + (dx - 1) * 32);
#pragma unroll
                for (int j = 0; j < 4; ++j) vr[dx][j] = vp[j];
            }
#pragma unroll
            for (int dx = 0; dx < 3; ++dx) {
                float pw = dots[(dz * 3 + dy) * 3 + dx];   // 0 for masked
#pragma unroll
                for (int j = 0; j < 4; ++j) {
                    uint4 u = vr[dx][j];
                    ov[j * 8 + 0] = fmaf(pw, bl(u.x), ov[j * 8 + 0]);
                    ov[j * 8 + 1] = fmaf(pw, bh(u.x), ov[j * 8 + 1]);
                    ov[j * 8 + 2] = fmaf(pw, bl(u.y), ov[j * 8 + 2]);
                    ov[j * 8 + 3] = fmaf(pw, bh(u.y), ov[j * 8 + 3]);
                    ov[j * 8 + 4] = fmaf(pw, bl(u.z), ov[j * 8 + 4]);
                    ov[j * 8 + 5] = fmaf(pw, bh(u.z), ov[j * 8 + 5]);
                    ov[j * 8 + 6] = fmaf(pw, bl(u.w), ov[j * 8 + 6]);
                    ov[j * 8 + 7] = fmaf(pw, bh(u.w), ov[j * 8 + 7]);
                }
            }
        }

    // attention tile -> LDS, pos-major rows, 16B units XOR-swizzled by row
#pragma unroll
    for (int j = 0; j < 4; ++j) {
        uint4 o;
        o.x = pk2(ov[j * 8 + 0] * inv, ov[j * 8 + 1] * inv);
        o.y = pk2(ov[j * 8 + 2] * inv, ov[j * 8 + 3] * inv);
        o.z = pk2(ov[j * 8 + 4] * inv, ov[j * 8 + 5] * inv);
        o.w = pk2(ov[j * 8 + 6] * inv, ov[j * 8 + 7] * inv);
        int unit = n * 4 + j;                   // 16B unit within the 512B row
        int su = unit ^ (w & 7);
        *(uint4*)&aol[w * 256 + su * 8] = o;
    }

    // ---- phase 2: out[32,256] = aol @ Wo + bo ----
    const int lane = threadIdx.x & 63;
    const int wv = threadIdx.x >> 6;            // wave -> col block of 64
    const int l15 = lane & 15, l4 = lane >> 4;

    f32x4 acc[2][4];
#pragma unroll
    for (int m2 = 0; m2 < 2; ++m2)
#pragma unroll
        for (int n2 = 0; n2 < 4; ++n2) acc[m2][n2] = (f32x4){0.f, 0.f, 0.f, 0.f};

    for (int kt = 0; kt < 4; ++kt) {
        __syncthreads();                        // aol ready / prev MFMA done with Bl
#pragma unroll
        for (int i = 0; i < 8; ++i) {           // stage Wo K-tile: 2048 16B units
            int u = threadIdx.x + i * 256;
            int rowb = u >> 3, su = u & 7;
            *(uint4*)&Bl[rowb][su * 8] =
                *(const uint4*)&wt3[(size_t)rowb * DIM_N + kt * 64 + su * 8];
        }
        __syncthreads();
#pragma unroll
        for (int ks = 0; ks < 2; ++ks) {
            bf16x8 af[2], bfr[4];
#pragma unroll
            for (int m2 = 0; m2 < 2; ++m2) {
                int r = m2 * 16 + l15;
                int unit = kt * 8 + ks * 4 + l4;
                int su = unit ^ (r & 7);
                af[m2] = *(const bf16x8*)&aol[r * 256 + su * 8];
            }
#pragma unroll
            for (int n2 = 0; n2 < 4; ++n2)
                bfr[n2] = *(const bf16x8*)&Bl[wv * 64 + n2 * 16 + l15][ks * 32 + l4 * 8];
#pragma unroll
            for (int m2 = 0; m2 < 2; ++m2)
#pragma unroll
                for (int n2 = 0; n2 < 4; ++n2)
                    acc[m2][n2] = __builtin_amdgcn_mfma_f32_16x16x32_bf16(
                        af[m2], bfr[n2], acc[m2][n2], 0, 0, 0);
        }
    }

#pragma unroll
    for (int n2 = 0; n2 < 4; ++n2) {
        int col = wv * 64 + n2 * 16 + l15;
        float bb = bo[col];
#pragma unroll
        for (int m2 = 0; m2 < 2; ++m2) {
#pragma unroll
            for (int rg = 0; rg < 4; ++rg) {
                int row = m2 * 16 + l4 * 4 + rg;
                out[(rowbase + row) * DIM_N + col] = acc[m2][n2][rg] + bb;
            }
        }
    }
}

// ---------------- launch ----------------
extern "C" void kernel_launch(void* const* d_in, const int* in_sizes, int n_in,
                              void* d_out, int out_size, void* d_ws, size_t ws_size,
                              hipStream_t stream)
{
    const float* xin = (const float*)d_in[0];
    const float* qin = (const float*)d_in[1];
    const float* Wq  = (const float*)d_in[2];
    const float* Wk  = (const float*)d_in[3];
    const float* Wv  = (const float*)d_in[4];
    const float* bv  = (const float*)d_in[5];
    const float* Wo  = (const float*)d_in[6];
    const float* bo  = (const float*)d_in[7];
    float* out = (float*)d_out;

    unsigned short* ws = (unsigned short*)d_ws;
    unsigned short* wt = ws;                        // 4 * 65536
    unsigned short* qh = wt + (size_t)4 * 65536;    // head-major [8][NPOS][32]
    unsigned short* kh = qh + (size_t)NP;
    unsigned short* vh = kh + (size_t)NP;

    dim3 gw(64, 4);
    wtrans_kernel<<<gw, 256, 0, stream>>>(Wq, Wk, Wv, Wo, wt);

    proj_mfma<<<768, 512, 0, stream>>>(xin, qin, wt, bv, qh, kh, vh);

    attn_fused<<<B_N * S_N * H_N, 256, 0, stream>>>(qh, kh, vh, wt + 3 * 65536, bo, out);
}

// Round 11
// 59.049 us; speedup vs baseline: 1.1101x; 1.0195x over previous
//
#include <hip/hip_runtime.h>
#include <hip/hip_bf16.h>
#include <math.h>

#define B_N 2
#define S_N 8
#define H_N 32
#define W_N 32
#define DIM_N 256
#define NPOS (B_N * S_N * H_N * W_N)       // 16384
#define NP (NPOS * DIM_N)                  // 4194304
#define SCALE_F 0.1767766952966369f        // 32^-0.5

typedef __attribute__((ext_vector_type(8))) short bf16x8;
typedef __attribute__((ext_vector_type(4))) float f32x4;

#if __has_builtin(__builtin_amdgcn_fdot2_f32_bf16)
#define HAS_DOT2 1
typedef __attribute__((ext_vector_type(2))) __bf16 bf16x2;
__device__ __forceinline__ bf16x2 b2(unsigned u) {
    return __builtin_bit_cast(bf16x2, u);
}
#else
#define HAS_DOT2 0
#endif

__device__ __forceinline__ unsigned short f2b(float f) {
    __hip_bfloat16 h = __float2bfloat16(f);
    return __builtin_bit_cast(unsigned short, h);
}
__device__ __forceinline__ unsigned pk2(float a, float b) {
    return (unsigned)f2b(a) | ((unsigned)f2b(b) << 16);
}
__device__ __forceinline__ float bl(unsigned u) { return __uint_as_float(u << 16); }
__device__ __forceinline__ float bh(unsigned u) { return __uint_as_float(u & 0xffff0000u); }

// ---------------- weight transpose + convert: Wt[n][k] = bf16(W[k][n]) ----------------
__global__ __launch_bounds__(256)
void wtrans_kernel(const float* __restrict__ Wq, const float* __restrict__ Wk,
                   const float* __restrict__ Wv, const float* __restrict__ Wo,
                   unsigned short* __restrict__ wt)
{
    int mat = blockIdx.y;
    const float* W = (mat == 0) ? Wq : (mat == 1) ? Wk : (mat == 2) ? Wv : Wo;
    unsigned short* Wt = wt + (size_t)mat * 65536;
    int tile = blockIdx.x;                 // 64 tiles of 32x32
    int tk = tile >> 3, tn = tile & 7;
    __shared__ float t[32][33];
    int c = threadIdx.x & 31;
    int r0 = (threadIdx.x >> 5) * 4;
#pragma unroll
    for (int i = 0; i < 4; ++i)
        t[r0 + i][c] = W[(size_t)(tk * 32 + r0 + i) * 256 + tn * 32 + c];
    __syncthreads();
#pragma unroll
    for (int i = 0; i < 4; ++i)
        Wt[(size_t)(tn * 32 + r0 + i) * 256 + tk * 32 + c] = f2b(t[c][r0 + i]);
}

// ---------------- proj GEMM: 64x256 tile, 8 waves (2r x 4n of 32x64), BK=64 --------
// A read exactly once (full-N tile). B staged via global_load_lds (linear LDS
// dest, inverse-swizzled global source, XOR-swizzled ds_read). A fp32 -> bf16
// inline through registers. 42KB LDS + launch_bounds(512,6) -> 3 blocks/CU,
// 24 waves/CU for latency hiding. out head-major bf16 [head][pos][32].
// (R10 structure — best measured; do not touch.)
__global__ __launch_bounds__(512, 6)
void proj_mfma(const float* __restrict__ x, const float* __restrict__ q,
               const unsigned short* __restrict__ wt, const float* __restrict__ bv,
               unsigned short* __restrict__ qh, unsigned short* __restrict__ kh,
               unsigned short* __restrict__ vh)
{
    __shared__ unsigned short Al[64][72];       // padded: 2-way max on frag reads
    __shared__ unsigned short Bl[256][64];      // linear: global_load_lds dest

    const int bx = blockIdx.x;                  // 256 rowtiles x 3 mats
    const int z = bx >> 8;                      // 0:q 1:k 2:v
    const int row0 = (bx & 255) * 64;
    const float* A = (z == 0) ? q : x;
    const unsigned short* Wtm = wt + (size_t)z * 65536;
    unsigned short* outp = (z == 0) ? qh : (z == 1) ? kh : vh;
    const float* bias = (z == 2) ? bv : nullptr;

    const int tid = threadIdx.x;
    const int lane = tid & 63;
    const int wid = tid >> 6;
    const int wr = wid >> 2, wn = wid & 3;      // wave tile: 32 rows x 64 cols
    const int l15 = lane & 15, l4 = lane >> 4;

    f32x4 acc[2][4];
#pragma unroll
    for (int m = 0; m < 2; ++m)
#pragma unroll
        for (int n = 0; n < 4; ++n) acc[m][n] = (f32x4){0.f, 0.f, 0.f, 0.f};

    for (int kt = 0; kt < DIM_N; kt += 64) {
        // B: 256 rows x 64 k via global_load_lds; physical unit u of row r
        // holds logical unit u^(r&7); read side applies the same XOR.
#pragma unroll
        for (int i = 0; i < 4; ++i) {
            int c = wid * 4 + i;                // chunk 0..31 (8 rows each)
            int o = c * 64 + lane;              // 16B-unit index 0..2047
            int row = o >> 3, u = o & 7;
            int lu = u ^ (row & 7);
            const unsigned short* g =
                &Wtm[(size_t)row * DIM_N + kt + lu * 8];
            __builtin_amdgcn_global_load_lds(
                (const __attribute__((address_space(1))) unsigned int*)g,
                (__attribute__((address_space(3))) unsigned int*)&Bl[c * 8][0],
                16, 0, 0);
        }
        // A: 64 rows x 64 k fp32 -> bf16; 1024 float4 units, 2 per thread
#pragma unroll
        for (int i = 0; i < 2; ++i) {
            int o = i * 512 + tid;
            int row = o >> 4, qq = o & 15;
            float4 f = *(const float4*)&A[(size_t)(row0 + row) * DIM_N + kt + qq * 4];
            uint2 v;
            v.x = pk2(f.x, f.y);
            v.y = pk2(f.z, f.w);
            *(uint2*)&Al[row][qq * 4] = v;
        }
        __syncthreads();
#pragma unroll
        for (int ks = 0; ks < 2; ++ks) {
            bf16x8 af[2], bfr[4];
#pragma unroll
            for (int m = 0; m < 2; ++m)
                af[m] = *(const bf16x8*)&Al[wr * 32 + m * 16 + l15][ks * 32 + l4 * 8];
#pragma unroll
            for (int n = 0; n < 4; ++n) {
                int row = wn * 64 + n * 16 + l15;
                int su = (ks * 4 + l4) ^ (row & 7);
                bfr[n] = *(const bf16x8*)&Bl[row][su * 8];
            }
#pragma unroll
            for (int m = 0; m < 2; ++m)
#pragma unroll
                for (int n = 0; n < 4; ++n)
                    acc[m][n] = __builtin_amdgcn_mfma_f32_16x16x32_bf16(
                        af[m], bfr[n], acc[m][n], 0, 0, 0);
        }
        __syncthreads();
    }

    // D layout: col = lane&15, row = (lane>>4)*4 + reg  [m89]
#pragma unroll
    for (int n = 0; n < 4; ++n) {
        int col = wn * 64 + n * 16 + l15;
        float bb = bias ? bias[col] : 0.f;
        int head = col >> 5, dh = col & 31;
#pragma unroll
        for (int m = 0; m < 2; ++m) {
#pragma unroll
            for (int rg = 0; rg < 4; ++rg) {
                int row = row0 + wr * 32 + m * 16 + l4 * 4 + rg;
                outp[((size_t)head * NPOS + row) * 32 + dh] =
                    f2b(acc[m][n][rg] + bb);
            }
        }
    }
}

// ---------------- fused local 3D attention + output projection ----------------
// Block = (b,s,h) row, 256 threads / 4 waves. XCD-chunked swizzle. Phase-1
// branchless; QK inner product via v_dot2_f32_bf16 (packed bf16 dot, halves
// unpack+fma op count) when available. Phase-2: Wo K-tiles LDS-staged, MFMA
// cluster wrapped in s_setprio (independent blocks at different phases).
__global__ __launch_bounds__(256, 2)
void attn_fused(const unsigned short* __restrict__ qh, const unsigned short* __restrict__ kh,
                const unsigned short* __restrict__ vh, const unsigned short* __restrict__ wt3,
                const float* __restrict__ bo, float* __restrict__ out)
{
    __shared__ unsigned short aol[32 * 256];    // 16 KB attention-output tile
    __shared__ unsigned short Bl[256][72];      // 36 KB Wo K-tile

    int p = blockIdx.x;
    int bix = (p & 7) * 64 + (p >> 3);          // bijective: 512 = 8 * 64
    int h = bix & 31, s = (bix >> 5) & 7, b = bix >> 8;
    int n = threadIdx.x >> 5;       // head
    int w = threadIdx.x & 31;

    size_t rowbase = (((size_t)b * S_N + s) * H_N + h) * W_N;
    size_t pos = rowbase + w;
    const unsigned short* qrow = qh + ((size_t)n * NPOS + pos) * 32;

#if HAS_DOT2
    bf16x2 qp[16];                  // q row kept packed
#pragma unroll
    for (int j = 0; j < 4; ++j) {
        uint4 u = ((const uint4*)qrow)[j];
        qp[j * 4 + 0] = b2(u.x); qp[j * 4 + 1] = b2(u.y);
        qp[j * 4 + 2] = b2(u.z); qp[j * 4 + 3] = b2(u.w);
    }
#else
    float qv[32];
#pragma unroll
    for (int j = 0; j < 4; ++j) {
        uint4 u = ((const uint4*)qrow)[j];
        qv[j * 8 + 0] = bl(u.x); qv[j * 8 + 1] = bh(u.x);
        qv[j * 8 + 2] = bl(u.y); qv[j * 8 + 3] = bh(u.y);
        qv[j * 8 + 4] = bl(u.z); qv[j * 8 + 5] = bh(u.z);
        qv[j * 8 + 6] = bl(u.w); qv[j * 8 + 7] = bh(u.w);
    }
#endif

    float dots[27];
#pragma unroll
    for (int dz = 0; dz < 3; ++dz)
#pragma unroll
        for (int dy = 0; dy < 3; ++dy) {
            int ns = s + dz - 1, nh = h + dy - 1;
            bool rowok = (unsigned)ns < S_N && (unsigned)nh < H_N;
            size_t rb = rowok ? ((((size_t)b * S_N + ns) * H_N + nh) * W_N)
                              : rowbase;
            const unsigned short* base = kh + ((size_t)n * NPOS + rb + w) * 32;
            uint4 kr[3][4];
#pragma unroll
            for (int dx = 0; dx < 3; ++dx) {
                const uint4* kp = (const uint4*)(base + (dx - 1) * 32);
#pragma unroll
                for (int j = 0; j < 4; ++j) kr[dx][j] = kp[j];
            }
#pragma unroll
            for (int dx = 0; dx < 3; ++dx) {
                float acc = 0.f;
#if HAS_DOT2
#pragma unroll
                for (int j = 0; j < 4; ++j) {
                    uint4 u = kr[dx][j];
                    acc = __builtin_amdgcn_fdot2_f32_bf16(b2(u.x), qp[j * 4 + 0], acc, false);
                    acc = __builtin_amdgcn_fdot2_f32_bf16(b2(u.y), qp[j * 4 + 1], acc, false);
                    acc = __builtin_amdgcn_fdot2_f32_bf16(b2(u.z), qp[j * 4 + 2], acc, false);
                    acc = __builtin_amdgcn_fdot2_f32_bf16(b2(u.w), qp[j * 4 + 3], acc, false);
                }
#else
#pragma unroll
                for (int j = 0; j < 4; ++j) {
                    uint4 u = kr[dx][j];
                    acc = fmaf(qv[j * 8 + 0], bl(u.x), acc);
                    acc = fmaf(qv[j * 8 + 1], bh(u.x), acc);
                    acc = fmaf(qv[j * 8 + 2], bl(u.y), acc);
                    acc = fmaf(qv[j * 8 + 3], bh(u.y), acc);
                    acc = fmaf(qv[j * 8 + 4], bl(u.z), acc);
                    acc = fmaf(qv[j * 8 + 5], bh(u.z), acc);
                    acc = fmaf(qv[j * 8 + 6], bl(u.w), acc);
                    acc = fmaf(qv[j * 8 + 7], bh(u.w), acc);
                }
#endif
                int nw = w + dx - 1;
                bool ok = rowok && (unsigned)nw < W_N;
                dots[(dz * 3 + dy) * 3 + dx] = ok ? acc * SCALE_F : -1e30f;
            }
        }

    float m = dots[0];
#pragma unroll
    for (int i = 1; i < 27; ++i) m = fmaxf(m, dots[i]);
    float den = 0.f;
#pragma unroll
    for (int i = 0; i < 27; ++i) {
        float p2 = __expf(dots[i] - m);     // masked: exp(-1e30) == 0 exactly
        dots[i] = p2;
        den += p2;
    }
    float inv = 1.f / den;

    float ov[32];
#pragma unroll
    for (int i = 0; i < 32; ++i) ov[i] = 0.f;
#pragma unroll
    for (int dz = 0; dz < 3; ++dz)
#pragma unroll
        for (int dy = 0; dy < 3; ++dy) {
            int ns = s + dz - 1, nh = h + dy - 1;
            bool rowok = (unsigned)ns < S_N && (unsigned)nh < H_N;
            size_t rb = rowok ? ((((size_t)b * S_N + ns) * H_N + nh) * W_N)
                              : rowbase;
            const unsigned short* base = vh + ((size_t)n * NPOS + rb + w) * 32;
            uint4 vr[3][4];
#pragma unroll
            for (int dx = 0; dx < 3; ++dx) {
                const uint4* vp = (const uint4*)(base + (dx - 1) * 32);
#pragma unroll
                for (int j = 0; j < 4; ++j) vr[dx][j] = vp[j];
            }
#pragma unroll
            for (int dx = 0; dx < 3; ++dx) {
                float pw = dots[(dz * 3 + dy) * 3 + dx];   // 0 for masked
#pragma unroll
                for (int j = 0; j < 4; ++j) {
                    uint4 u = vr[dx][j];
                    ov[j * 8 + 0] = fmaf(pw, bl(u.x), ov[j * 8 + 0]);
                    ov[j * 8 + 1] = fmaf(pw, bh(u.x), ov[j * 8 + 1]);
                    ov[j * 8 + 2] = fmaf(pw, bl(u.y), ov[j * 8 + 2]);
                    ov[j * 8 + 3] = fmaf(pw, bh(u.y), ov[j * 8 + 3]);
                    ov[j * 8 + 4] = fmaf(pw, bl(u.z), ov[j * 8 + 4]);
                    ov[j * 8 + 5] = fmaf(pw, bh(u.z), ov[j * 8 + 5]);
                    ov[j * 8 + 6] = fmaf(pw, bl(u.w), ov[j * 8 + 6]);
                    ov[j * 8 + 7] = fmaf(pw, bh(u.w), ov[j * 8 + 7]);
                }
            }
        }

    // attention tile -> LDS, pos-major rows, 16B units XOR-swizzled by row
#pragma unroll
    for (int j = 0; j < 4; ++j) {
        uint4 o;
        o.x = pk2(ov[j * 8 + 0] * inv, ov[j * 8 + 1] * inv);
        o.y = pk2(ov[j * 8 + 2] * inv, ov[j * 8 + 3] * inv);
        o.z = pk2(ov[j * 8 + 4] * inv, ov[j * 8 + 5] * inv);
        o.w = pk2(ov[j * 8 + 6] * inv, ov[j * 8 + 7] * inv);
        int unit = n * 4 + j;                   // 16B unit within the 512B row
        int su = unit ^ (w & 7);
        *(uint4*)&aol[w * 256 + su * 8] = o;
    }

    // ---- phase 2: out[32,256] = aol @ Wo + bo ----
    const int lane = threadIdx.x & 63;
    const int wv = threadIdx.x >> 6;            // wave -> col block of 64
    const int l15 = lane & 15, l4 = lane >> 4;

    f32x4 acc[2][4];
#pragma unroll
    for (int m2 = 0; m2 < 2; ++m2)
#pragma unroll
        for (int n2 = 0; n2 < 4; ++n2) acc[m2][n2] = (f32x4){0.f, 0.f, 0.f, 0.f};

    for (int kt = 0; kt < 4; ++kt) {
        __syncthreads();                        // aol ready / prev MFMA done with Bl
#pragma unroll
        for (int i = 0; i < 8; ++i) {           // stage Wo K-tile: 2048 16B units
            int u = threadIdx.x + i * 256;
            int rowb = u >> 3, su = u & 7;
            *(uint4*)&Bl[rowb][su * 8] =
                *(const uint4*)&wt3[(size_t)rowb * DIM_N + kt * 64 + su * 8];
        }
        __syncthreads();
#pragma unroll
        for (int ks = 0; ks < 2; ++ks) {
            bf16x8 af[2], bfr[4];
#pragma unroll
            for (int m2 = 0; m2 < 2; ++m2) {
                int r = m2 * 16 + l15;
                int unit = kt * 8 + ks * 4 + l4;
                int su = unit ^ (r & 7);
                af[m2] = *(const bf16x8*)&aol[r * 256 + su * 8];
            }
#pragma unroll
            for (int n2 = 0; n2 < 4; ++n2)
                bfr[n2] = *(const bf16x8*)&Bl[wv * 64 + n2 * 16 + l15][ks * 32 + l4 * 8];
            __builtin_amdgcn_s_setprio(1);
#pragma unroll
            for (int m2 = 0; m2 < 2; ++m2)
#pragma unroll
                for (int n2 = 0; n2 < 4; ++n2)
                    acc[m2][n2] = __builtin_amdgcn_mfma_f32_16x16x32_bf16(
                        af[m2], bfr[n2], acc[m2][n2], 0, 0, 0);
            __builtin_amdgcn_s_setprio(0);
        }
    }

#pragma unroll
    for (int n2 = 0; n2 < 4; ++n2) {
        int col = wv * 64 + n2 * 16 + l15;
        float bb = bo[col];
#pragma unroll
        for (int m2 = 0; m2 < 2; ++m2) {
#pragma unroll
            for (int rg = 0; rg < 4; ++rg) {
                int row = m2 * 16 + l4 * 4 + rg;
                out[(rowbase + row) * DIM_N + col] = acc[m2][n2][rg] + bb;
            }
        }
    }
}

// ---------------- launch ----------------
extern "C" void kernel_launch(void* const* d_in, const int* in_sizes, int n_in,
                              void* d_out, int out_size, void* d_ws, size_t ws_size,
                              hipStream_t stream)
{
    const float* xin = (const float*)d_in[0];
    const float* qin = (const float*)d_in[1];
    const float* Wq  = (const float*)d_in[2];
    const float* Wk  = (const float*)d_in[3];
    const float* Wv  = (const float*)d_in[4];
    const float* bv  = (const float*)d_in[5];
    const float* Wo  = (const float*)d_in[6];
    const float* bo  = (const float*)d_in[7];
    float* out = (float*)d_out;

    unsigned short* ws = (unsigned short*)d_ws;
    unsigned short* wt = ws;                        // 4 * 65536
    unsigned short* qh = wt + (size_t)4 * 65536;    // head-major [8][NPOS][32]
    unsigned short* kh = qh + (size_t)NP;
    unsigned short* vh = kh + (size_t)NP;

    dim3 gw(64, 4);
    wtrans_kernel<<<gw, 256, 0, stream>>>(Wq, Wk, Wv, Wo, wt);

    proj_mfma<<<768, 512, 0, stream>>>(xin, qin, wt, bv, qh, kh, vh);

    attn_fused<<<B_N * S_N * H_N, 256, 0, stream>>>(qh, kh, vh, wt + 3 * 65536, bo, out);
}